// Round 2
// baseline (365.870 us; speedup 1.0000x reference)
//
#include <hip/hip_runtime.h>
#include <hip/hip_bf16.h>

#define N_RAYS 262144
#define N_PTS  64
#define FAR_DELTA 1e10f

#define RPB 64          // rays per block == threads per block (1 wave)
#define ST  16          // samples per tile
#define NT  (N_PTS/ST)  // 4 tiles

#define DS_STRIDE 17    // 16 samples + 1 pad (odd -> conflict-free column reads)
#define FT_STRIDE 49    // 48 feature floats + 1 pad (odd)

__global__ __launch_bounds__(64) void volume_render_kernel(
    const float* __restrict__ density,       // (N, 64, 1)
    const float* __restrict__ depth_values,  // (N, 64)
    const float* __restrict__ rays_feature,  // (N, 64, 3)
    float* __restrict__ out)                 // feature (N*3) then depth (N)
{
    __shared__ float s_dens[RPB * DS_STRIDE];  // 4352 B
    __shared__ float s_dep [RPB * DS_STRIDE];  // 4352 B
    __shared__ float s_feat[RPB * FT_STRIDE];  // 12544 B  (total ~21 KB -> 7 blocks/CU)

    const int t    = threadIdx.x;        // 0..63, one ray per thread
    const int ray0 = blockIdx.x * RPB;

    // Per-ray sequential state: running transmittance + carried previous sample.
    float T = 1.0f;
    float ax = 0.f, ay = 0.f, az = 0.f, ad = 0.f;
    float sig_p = 0.f, d_p = 0.f, fx_p = 0.f, fy_p = 0.f, fz_p = 0.f;

    #pragma unroll
    for (int tile = 0; tile < NT; ++tile) {
        const int s0 = tile * ST;
        __syncthreads();  // protect LDS from previous tile's readers (1 wave: cheap)

        // ---- stage density & depth: 64 rays x 16 floats = 256 float4 each ----
        #pragma unroll
        for (int i = 0; i < 4; ++i) {
            const unsigned flat = i * 64u + t;       // 0..255
            const int r = flat >> 2;                 // ray-local 0..63
            const int q = flat & 3;                  // 16B quad within the ray's tile
            const size_t g = (size_t)(ray0 + r) * N_PTS + s0 + q * 4;
            const float4 dv = *(const float4*)(density + g);
            const float4 zv = *(const float4*)(depth_values + g);
            float* dd = &s_dens[r * DS_STRIDE + q * 4];
            float* zz = &s_dep [r * DS_STRIDE + q * 4];
            dd[0] = dv.x; dd[1] = dv.y; dd[2] = dv.z; dd[3] = dv.w;
            zz[0] = zv.x; zz[1] = zv.y; zz[2] = zv.z; zz[3] = zv.w;
        }
        // ---- stage features: 64 rays x 48 floats = 768 float4 ----
        #pragma unroll
        for (int i = 0; i < 12; ++i) {
            const unsigned flat = i * 64u + t;       // 0..767
            const unsigned r = flat / 12u;           // ray-local 0..63
            const unsigned q = flat - r * 12u;       // 0..11
            const size_t g = (size_t)(ray0 + r) * (N_PTS * 3) + s0 * 3 + q * 4;
            const float4 fv = *(const float4*)(rays_feature + g);
            float* ff = &s_feat[r * FT_STRIDE + q * 4];
            ff[0] = fv.x; ff[1] = fv.y; ff[2] = fv.z; ff[3] = fv.w;
        }
        __syncthreads();

        // ---- sequential scan over this tile's samples (zero cross-lane ops) ----
        #pragma unroll
        for (int j = 0; j < ST; ++j) {
            const float d  = s_dep [t * DS_STRIDE + j];
            const float sg = s_dens[t * DS_STRIDE + j];
            const float fx = s_feat[t * FT_STRIDE + 3 * j + 0];
            const float fy = s_feat[t * FT_STRIDE + 3 * j + 1];
            const float fz = s_feat[t * FT_STRIDE + 3 * j + 2];
            if (tile > 0 || j > 0) {   // folds at compile time (both loops unrolled)
                const float delta = d - d_p;
                const float e = __expf(-sig_p * delta);
                const float w = T * (1.0f - e);
                ax += w * fx_p; ay += w * fy_p; az += w * fz_p; ad += w * d_p;
                T *= e;
            }
            sig_p = sg; d_p = d; fx_p = fx; fy_p = fy; fz_p = fz;
        }
    }

    // ---- final sample: far-plane sentinel delta ----
    {
        const float e = __expf(-sig_p * FAR_DELTA);  // sig_p==0 -> e=1 -> w=0, matches ref
        const float w = T * (1.0f - e);
        ax += w * fx_p; ay += w * fy_p; az += w * fz_p; ad += w * d_p;
    }

    const int ray = ray0 + t;
    out[(size_t)ray * 3 + 0] = ax;
    out[(size_t)ray * 3 + 1] = ay;
    out[(size_t)ray * 3 + 2] = az;
    out[(size_t)N_RAYS * 3 + ray] = ad;
}

extern "C" void kernel_launch(void* const* d_in, const int* in_sizes, int n_in,
                              void* d_out, int out_size, void* d_ws, size_t ws_size,
                              hipStream_t stream) {
    const float* density      = (const float*)d_in[0];
    const float* depth_values = (const float*)d_in[1];
    const float* rays_feature = (const float*)d_in[2];
    float* out = (float*)d_out;

    const int blocks = N_RAYS / RPB;  // 4096
    volume_render_kernel<<<blocks, RPB, 0, stream>>>(
        density, depth_values, rays_feature, out);
}